// Round 10
// baseline (375.020 us; speedup 1.0000x reference)
//
#include <hip/hip_runtime.h>

typedef unsigned short u16;
typedef unsigned int   u32;
typedef unsigned long long u64;
typedef __bf16 bf16x8 __attribute__((ext_vector_type(8)));
typedef float  f32x4  __attribute__((ext_vector_type(4)));

// Problem constants
#define NE    6          // experts
#define MTOT  4096       // B*S
#define CC    512        // C
#define BMAT  262144     // 512*512
#define EMAT  2097152    // 4096*512

// ws layout (bytes). Total need ~154.2 MB.
#define FLAG_OFF 0
#define XBF_OFF  256
#define WT_OFF   (XBF_OFF + MTOT*CC*2)          // x bf16: 4 MB
#define QBF_OFF  (WT_OFF  + 30*BMAT*2)          // 30 transposed bf16 weights: 15.7 MB
#define KBF_OFF  (QBF_OFF + NE*EMAT*2)
#define VT_OFF   (KBF_OFF + NE*EMAT*2)
#define XO_OFF   (VT_OFF  + NE*EMAT*2)
#define HBF_OFF  (XO_OFF  + NE*EMAT*2)
#define RH_OFF   (HBF_OFF + NE*EMAT*2)          // rh fp32: 8 MB

__device__ __forceinline__ u16 f2bf(float f) {
    u32 u = __float_as_uint(f);
    u32 r = (u + 0x7FFFu + ((u >> 16) & 1u)) >> 16;
    return (u16)r;
}
__device__ __forceinline__ u16 f2bf_hw(float f) {   // native RNE cvt (1 VALU op)
    __bf16 h = (__bf16)f;
    return *(u16*)&h;
}
__device__ __forceinline__ float bf2f(u16 h) {
    return __uint_as_float(((u32)h) << 16);
}
// native 2^x as a COMPILER-KNOWN instruction: MFMA->VALU and TRANS-latency
// hazards are software-managed; the hazard recognizer only protects known
// instructions. NO INLINE ASM may touch the MFMA/TRANS dataflow (R2: asm exp
// read the MFMA accumulator early -> NaN; R3: asm cvt_pk read the TRANS exp
// result early -> sporadic garbage P).
__device__ __forceinline__ float exp2_native(float x) {
#if __has_builtin(__builtin_amdgcn_exp2f)
    return __builtin_amdgcn_exp2f(x);
#else
    return exp2f(x);
#endif
}
__device__ __forceinline__ float gelu_exact(float x) {
    return 0.5f * x * (1.0f + erff(x * 0.70710678118654752f));
}
__device__ __forceinline__ bool mask_valid(const void* mask, int flag, int b, int t) {
    int idx = b * 1536 + t;   // mask is (B, 3S), use first S cols
    if (flag == 1) return ((const int*)mask)[idx] != 0;
    if (flag == 2) return ((const float*)mask)[idx] != 0.0f;
    return ((const unsigned char*)mask)[idx] != 0;
}

// ---------- mask dtype detection (bool may arrive as u8 / i32 / f32) ----------
__global__ void detect_mask_k(const u32* __restrict__ m, int* __restrict__ flag) {
    __shared__ int notint, notfloat;
    if (threadIdx.x == 0) { notint = 0; notfloat = 0; }
    __syncthreads();
    int ni = 0, nf = 0;
    for (int i = threadIdx.x; i < 3072; i += 256) {
        u32 v = m[i];
        if (v > 1u) ni = 1;
        if (v != 0u && v != 0x3F800000u) nf = 1;
    }
    if (ni) notint = 1;
    if (nf) notfloat = 1;
    __syncthreads();
    if (threadIdx.x == 0) *flag = (notint == 0) ? 1 : ((notfloat == 0) ? 2 : 0);
}

// ---------- x fp32 -> bf16 ----------
__global__ __launch_bounds__(256) void cast_x_k(const float* __restrict__ x, u16* __restrict__ xbf) {
    int i = blockIdx.x * 256 + threadIdx.x;
    float4 v = ((const float4*)x)[i];
    u64 pk = (u64)f2bf(v.x) | ((u64)f2bf(v.y) << 16) | ((u64)f2bf(v.z) << 32) | ((u64)f2bf(v.w) << 48);
    *(u64*)(xbf + (size_t)i * 4) = pk;
}

// ---------- weights fp32 [k][n] -> bf16 transposed [n][k] ----------
__global__ __launch_bounds__(256) void transpose_w_k(
    const float* __restrict__ qw, const float* __restrict__ kw, const float* __restrict__ vw,
    const float* __restrict__ f1w, const float* __restrict__ f2w, u16* __restrict__ wt) {
    int mat = blockIdx.y;
    int tile = blockIdx.x;
    int tr = tile >> 4, tc = tile & 15;
    const float* srcs[5] = {qw, kw, vw, f1w, f2w};
    const float* src = srcs[mat / 6] + (size_t)(mat % 6) * BMAT;
    u16* dst = wt + (size_t)mat * BMAT;
    __shared__ float tb[32][33];
    int r = threadIdx.x >> 5, c = threadIdx.x & 31;
    #pragma unroll
    for (int i = 0; i < 4; ++i)
        tb[r + i * 8][c] = src[(size_t)(tr * 32 + r + i * 8) * CC + tc * 32 + c];
    __syncthreads();
    #pragma unroll
    for (int i = 0; i < 4; ++i)
        dst[(size_t)(tc * 32 + r + i * 8) * CC + tr * 32 + c] = f2bf(tb[c][r + i * 8]);
}

// ---------- fp32 tiled GEMM for router rh = gelu(X @ rw1 + rb1) ----------
// R9: A-tile stored TRANSPOSED At[k][m]: inner loop reads a[0..3] as one broadcast
// ds_read_b128 and b[0..3] as one 2-way b128 (vs 8 scalar b32). Accumulation order
// unchanged -> bit-identical rh; router stays fp32-exact (top-2 must not flip).
__global__ __launch_bounds__(256) void router_rh_k(
    const float* __restrict__ x, const float* __restrict__ rw1, const float* __restrict__ rb1,
    float* __restrict__ rh) {
    const int n0 = blockIdx.x * 64, m0 = blockIdx.y * 64;
    const int tid = threadIdx.x, tx = tid & 15, ty = tid >> 4;
    __shared__ float At[16][68];
    __shared__ float Bs[16][68];
    float acc[4][4] = {};
    for (int kt = 0; kt < 32; ++kt) {
        int ar = tid >> 2, ak = (tid & 3) * 4;
        float4 av = *(const float4*)(x + (size_t)(m0 + ar) * CC + kt * 16 + ak);
        int br = tid >> 4, bn = (tid & 15) * 4;
        float4 bv = *(const float4*)(rw1 + (size_t)(kt * 16 + br) * CC + n0 + bn);
        __syncthreads();
        At[ak + 0][ar] = av.x; At[ak + 1][ar] = av.y;
        At[ak + 2][ar] = av.z; At[ak + 3][ar] = av.w;
        *(float4*)&Bs[br][bn] = bv;
        __syncthreads();
        #pragma unroll
        for (int k = 0; k < 16; ++k) {
            float4 a4 = *(const float4*)&At[k][ty * 4];
            float4 b4 = *(const float4*)&Bs[k][tx * 4];
            acc[0][0] = fmaf(a4.x, b4.x, acc[0][0]); acc[0][1] = fmaf(a4.x, b4.y, acc[0][1]);
            acc[0][2] = fmaf(a4.x, b4.z, acc[0][2]); acc[0][3] = fmaf(a4.x, b4.w, acc[0][3]);
            acc[1][0] = fmaf(a4.y, b4.x, acc[1][0]); acc[1][1] = fmaf(a4.y, b4.y, acc[1][1]);
            acc[1][2] = fmaf(a4.y, b4.z, acc[1][2]); acc[1][3] = fmaf(a4.y, b4.w, acc[1][3]);
            acc[2][0] = fmaf(a4.z, b4.x, acc[2][0]); acc[2][1] = fmaf(a4.z, b4.y, acc[2][1]);
            acc[2][2] = fmaf(a4.z, b4.z, acc[2][2]); acc[2][3] = fmaf(a4.z, b4.w, acc[2][3]);
            acc[3][0] = fmaf(a4.w, b4.x, acc[3][0]); acc[3][1] = fmaf(a4.w, b4.y, acc[3][1]);
            acc[3][2] = fmaf(a4.w, b4.z, acc[3][2]); acc[3][3] = fmaf(a4.w, b4.w, acc[3][3]);
        }
    }
    #pragma unroll
    for (int i = 0; i < 4; ++i) {
        int m = m0 + ty * 4 + i;
        #pragma unroll
        for (int j = 0; j < 4; ++j) {
            int n = n0 + tx * 4 + j;
            rh[(size_t)m * CC + n] = gelu_exact(acc[i][j] + rb1[n]);
        }
    }
}

// ---------- router: logits, softmax, top-2, normalized sparse weights ----------
__global__ __launch_bounds__(256) void router_topk_k(
    const float* __restrict__ rh, const float* __restrict__ rw2, const float* __restrict__ rb2,
    float* __restrict__ sparse) {
    int row = blockIdx.x * 4 + (threadIdx.x >> 6);
    int lane = threadIdx.x & 63;
    float acc[NE] = {};
    const float* rr = rh + (size_t)row * CC;
    for (int c = 0; c < 8; ++c) {
        int k = c * 64 + lane;
        float v = rr[k];
        const float* w = rw2 + (size_t)k * NE;
        #pragma unroll
        for (int e = 0; e < NE; ++e) acc[e] = fmaf(v, w[e], acc[e]);
    }
    #pragma unroll
    for (int off = 32; off; off >>= 1)
        #pragma unroll
        for (int e = 0; e < NE; ++e) acc[e] += __shfl_down(acc[e], off);
    if (lane == 0) {
        float lg[NE], m = -1e30f;
        #pragma unroll
        for (int e = 0; e < NE; ++e) { lg[e] = acc[e] + rb2[e]; m = fmaxf(m, lg[e]); }
        float s = 0.f, wv[NE];
        #pragma unroll
        for (int e = 0; e < NE; ++e) { wv[e] = expf(lg[e] - m); s += wv[e]; }
        #pragma unroll
        for (int e = 0; e < NE; ++e) wv[e] /= s;
        int i1 = 0; float v1 = wv[0];
        #pragma unroll
        for (int e = 1; e < NE; ++e) if (wv[e] > v1) { v1 = wv[e]; i1 = e; }
        int i2 = -1; float v2 = -1.f;
        #pragma unroll
        for (int e = 0; e < NE; ++e) if (e != i1 && wv[e] > v2) { v2 = wv[e]; i2 = e; }
        float denom = fmaxf(v1 + v2, 1e-8f);
        #pragma unroll
        for (int e = 0; e < NE; ++e)
            sparse[(size_t)row * NE + e] = ((e == i1) ? v1 : (e == i2) ? v2 : 0.f) / denom;
    }
}

// ---------- bf16 MFMA GEMM, compile-time MODE epilogue ----------
// MODE 0: Q = (x@qwT + qb)*scale*log2e -> bf16  (A=xbf shared across e; log2e folded so attn uses exp2)
// MODE 1: K =  x@kwT + kb        -> bf16
// MODE 2: V =  x@vwT + vb        -> bf16 TRANSPOSED [e][n][m_perm]  (m permuted per 32-block, see attn)
// MODE 3: H = gelu(xo@fc1T + b)  -> bf16      (A=xobf per e)
// MODE 4: stacked = xo + H@fc2T + b -> fp32   (A=hbf per e, resid=xobf)
// R10: BK=64 (was 32). Gemms were barrier-latency-bound: 16 iterations each exposing
// ~600cy load latency against only ~80cy of MFMA. BK=64 halves the exposures (8 iters),
// doubles in-flight staging bytes (8x16B/thread), and doubles per-iteration compute
// (32 MFMA ~155cy) to overlap the next iteration's loads. LDS 2x128x72x2B = 36.9KB
// (3 blocks/CU intact -- avoids m132's BK=128 cliff). Stride 72 u16: write pattern
// 4r+16h mod 32 and read pattern 4r -> 2-way bank aliasing = free (m136).
// Accumulation order is the identical ascending-k sequence -> bit-identical output.
// R8 lesson kept: reg-staged (loads issue BEFORE the barrier = free prefetch phase);
// single-buffered gload_lds phase-locks at short K (69us, MfmaUtil 6.8%).
template<int MODE>
__global__ __launch_bounds__(256, 3) void gemm_k(
    const u16* __restrict__ A0, const u16* __restrict__ wt,
    u16* __restrict__ out_bf, float* __restrict__ out_f32,
    const u16* __restrict__ resid, const float* __restrict__ bias0) {
    const int e = blockIdx.z;
    const u16* A  = (MODE <= 2) ? A0 : (A0 + (size_t)e * EMAT);
    const int wmat = (MODE == 0 ? 0 : MODE == 1 ? 6 : MODE == 2 ? 12 : MODE == 3 ? 18 : 24) + e;
    const u16* BT = wt + (size_t)wmat * BMAT;
    const float* bias = bias0 + e * CC;

    const int m0 = blockIdx.y * 128, n0 = blockIdx.x * 128;
    const int tid = threadIdx.x, lane = tid & 63, wv = tid >> 6;
    const int l15 = lane & 15, quad = lane >> 4;
    const int wr = (wv >> 1) * 64, wc = (wv & 1) * 64;

    __shared__ u16 As[128 * 72];
    __shared__ u16 Bs[128 * 72];

    f32x4 acc[4][4];
    f32x4 z4 = {0.f, 0.f, 0.f, 0.f};
    #pragma unroll
    for (int i = 0; i < 4; ++i)
        #pragma unroll
        for (int j = 0; j < 4; ++j) acc[i][j] = z4;

    // staging: 128 rows x 64 cols u16 per matrix; 2 threads/row, 64B (4 x uint4) each
    const int row2 = tid >> 1, half = tid & 1;
    const u16* agp = A  + (size_t)(m0 + row2) * CC + half * 32;
    const u16* bgp = BT + (size_t)(n0 + row2) * CC + half * 32;
    u16* asp = As + row2 * 72 + half * 32;
    u16* bsp = Bs + row2 * 72 + half * 32;

    for (int kt = 0; kt < 8; ++kt) {
        uint4 a0 = *(const uint4*)(agp + kt * 64);
        uint4 a1 = *(const uint4*)(agp + kt * 64 + 8);
        uint4 a2 = *(const uint4*)(agp + kt * 64 + 16);
        uint4 a3 = *(const uint4*)(agp + kt * 64 + 24);
        uint4 b0 = *(const uint4*)(bgp + kt * 64);
        uint4 b1 = *(const uint4*)(bgp + kt * 64 + 8);
        uint4 b2 = *(const uint4*)(bgp + kt * 64 + 16);
        uint4 b3 = *(const uint4*)(bgp + kt * 64 + 24);
        __syncthreads();
        *(uint4*)asp = a0; *(uint4*)(asp + 8)  = a1;
        *(uint4*)(asp + 16) = a2; *(uint4*)(asp + 24) = a3;
        *(uint4*)bsp = b0; *(uint4*)(bsp + 8)  = b1;
        *(uint4*)(bsp + 16) = b2; *(uint4*)(bsp + 24) = b3;
        __syncthreads();
        #pragma unroll
        for (int s = 0; s < 2; ++s) {
            bf16x8 af[4], bf[4];
            #pragma unroll
            for (int i = 0; i < 4; ++i)
                af[i] = *(const bf16x8*)(As + (wr + i * 16 + l15) * 72 + s * 32 + quad * 8);
            #pragma unroll
            for (int j = 0; j < 4; ++j)
                bf[j] = *(const bf16x8*)(Bs + (wc + j * 16 + l15) * 72 + s * 32 + quad * 8);
            #pragma unroll
            for (int i = 0; i < 4; ++i)
                #pragma unroll
                for (int j = 0; j < 4; ++j)
                    acc[i][j] = __builtin_amdgcn_mfma_f32_16x16x32_bf16(af[i], bf[j], acc[i][j], 0, 0, 0);
        }
    }

    #pragma unroll
    for (int i = 0; i < 4; ++i) {
        int mb = m0 + wr + i * 16 + quad * 4;
        #pragma unroll
        for (int j = 0; j < 4; ++j) {
            int n = n0 + wc + j * 16 + l15;
            float bvs = bias[n];
            if (MODE == 2) {
                // V: transposed store [e][n][m_perm]. Within each 32-key block of m,
                // key km = hi*16 + q*4 + r is stored at position q*8 + hi*4 + r, so the
                // attn PV B-fragment (lane quad reads 8 keys {q*4+0..3, 16+q*4+0..3})
                // is one contiguous 16B load at offset quad*8.
                u16 pk[4];
                #pragma unroll
                for (int r = 0; r < 4; ++r) pk[r] = f2bf(acc[i][j][r] + bvs);
                u64 w8 = (u64)pk[0] | ((u64)pk[1] << 16) | ((u64)pk[2] << 32) | ((u64)pk[3] << 48);
                int mp = (mb & ~31) | (((mb >> 2) & 3) << 3) | (((mb >> 4) & 1) << 2);
                *(u64*)(out_bf + (size_t)e * EMAT + (size_t)n * MTOT + mp) = w8;
            } else if (MODE == 0 || MODE == 1) {
                #pragma unroll
                for (int r = 0; r < 4; ++r) {
                    float v = acc[i][j][r] + bvs;
                    // 0.125 * log2(e): attn computes exp2 directly (1 VTRANS, no pre-mul)
                    out_bf[(size_t)e * EMAT + (size_t)(mb + r) * CC + n] =
                        f2bf(MODE == 0 ? v * 0.18033688011112042f : v);
                }
            } else if (MODE == 3) {
                #pragma unroll
                for (int r = 0; r < 4; ++r)
                    out_bf[(size_t)e * EMAT + (size_t)(mb + r) * CC + n] = f2bf(gelu_exact(acc[i][j][r] + bvs));
            } else {
                #pragma unroll
                for (int r = 0; r < 4; ++r) {
                    int m = mb + r;
                    float v = acc[i][j][r] + bvs + bf2f(resid[(size_t)e * EMAT + (size_t)m * CC + n]);
                    out_f32[((size_t)m * NE + e) * CC + n] = v;
                }
            }
        }
    }
}

// ---------- flash attention v6: swapped QK^T, in-register P, permuted V, loads-at-use ----------
// S^T = mfma(K, Q): lane holds P for one q-row (q = lane&15) at keys {quad*4+r, 16+quad*4+r}.
// P packed to a bf16x8 PV A-fragment via constant-index vector inserts (SSA; compiler emits
// v_cvt_pk_bf16_f32 pairs). V STORED permuted (gemm_k<2>) so its B-fragment is one 16B load.
// No LDS P round-trip, no bank conflicts, no cross-lane ops.
// REGISTER BUDGET (R4/R5 lesson): __launch_bounds__(256,3) caps unified VGPR+AGPR at ~168.
// Deep register pipelines spill (WRITE_SIZE 950 MB signature). Per-chunk NAMED K/V
// temporaries, loads-at-use, ~150 regs, no spill. Known limit (R6/R9 counters):
// memory-latency-bound at 18% HBM.
// Correctness invariant (R2/R3): ZERO inline asm in the MFMA/TRANS dataflow.
// grid (2, b*8+h, e); block 256 (4 independent waves).
__global__ __launch_bounds__(256, 3) void attn_flash_k(
    const u16* __restrict__ qbf, const u16* __restrict__ kbf, const u16* __restrict__ vt,
    u16* __restrict__ xobf, const void* __restrict__ mask, const int* __restrict__ flagp) {
    const int b = blockIdx.y >> 3, h = blockIdx.y & 7;
    const int e = blockIdx.z;
    const int tid = threadIdx.x, lane = tid & 63, w = tid >> 6;
    const int l15 = lane & 15, quad = lane >> 4;
    const int s0 = blockIdx.x * 256 + w * 64;     // this wave's 64 q-rows (local s)
    const int flag = *flagp;

    // mask as float, staged once (2 KB LDS). Read per chunk as two float4.
    __shared__ float mlds[512];
    mlds[tid]       = mask_valid(mask, flag, b, tid)       ? 1.f : 0.f;
    mlds[tid + 256] = mask_valid(mask, flag, b, tid + 256) ? 1.f : 0.f;
    __syncthreads();

    const u16* qbase = qbf + (size_t)e * EMAT + (size_t)(b * 512) * CC + h * 64;
    const u16* kbase = kbf + (size_t)e * EMAT + (size_t)(b * 512) * CC + h * 64;
    const u16* vbase = vt  + (size_t)e * EMAT + (size_t)(h * 64) * MTOT + b * 512;

    bf16x8 qa[4][2];
    #pragma unroll
    for (int t = 0; t < 4; ++t) {
        qa[t][0] = *(const bf16x8*)(qbase + (size_t)(s0 + t * 16 + l15) * CC + quad * 8);
        qa[t][1] = *(const bf16x8*)(qbase + (size_t)(s0 + t * 16 + l15) * CC + 32 + quad * 8);
    }

    float lsum[4] = {0.f, 0.f, 0.f, 0.f};
    f32x4 o[4][4];
    f32x4 z4 = {0.f, 0.f, 0.f, 0.f};
    #pragma unroll
    for (int t = 0; t < 4; ++t)
        #pragma unroll
        for (int j = 0; j < 4; ++j) o[t][j] = z4;

    for (int ch = 0; ch < 16; ++ch) {
        const int k0 = ch * 32;
        // K fragments, loaded at use (named temporaries -- per-chunk lifetime only)
        bf16x8 kb00 = *(const bf16x8*)(kbase + (size_t)(k0 + l15) * CC + quad * 8);
        bf16x8 kb01 = *(const bf16x8*)(kbase + (size_t)(k0 + l15) * CC + 32 + quad * 8);
        bf16x8 kb10 = *(const bf16x8*)(kbase + (size_t)(k0 + 16 + l15) * CC + quad * 8);
        bf16x8 kb11 = *(const bf16x8*)(kbase + (size_t)(k0 + 16 + l15) * CC + 32 + quad * 8);
        // V fragments: single 16B load each thanks to the permuted store
        bf16x8 vf0 = *(const bf16x8*)(vbase + (size_t)(0 * 16 + l15) * MTOT + k0 + quad * 8);
        bf16x8 vf1 = *(const bf16x8*)(vbase + (size_t)(1 * 16 + l15) * MTOT + k0 + quad * 8);
        bf16x8 vf2 = *(const bf16x8*)(vbase + (size_t)(2 * 16 + l15) * MTOT + k0 + quad * 8);
        bf16x8 vf3 = *(const bf16x8*)(vbase + (size_t)(3 * 16 + l15) * MTOT + k0 + quad * 8);
        float4 m0v = *(const float4*)(mlds + k0 + quad * 4);
        float4 m1v = *(const float4*)(mlds + k0 + 16 + quad * 4);

        #pragma unroll
        for (int t = 0; t < 4; ++t) {
            f32x4 c0 = z4, c1 = z4;
            c0 = __builtin_amdgcn_mfma_f32_16x16x32_bf16(kb00, qa[t][0], c0, 0, 0, 0);
            c0 = __builtin_amdgcn_mfma_f32_16x16x32_bf16(kb01, qa[t][1], c0, 0, 0, 0);
            c1 = __builtin_amdgcn_mfma_f32_16x16x32_bf16(kb10, qa[t][0], c1, 0, 0, 0);
            c1 = __builtin_amdgcn_mfma_f32_16x16x32_bf16(kb11, qa[t][1], c1, 0, 0, 0);
            // lane: S^T[key = quad*4+r (c0) / 16+quad*4+r (c1)][q = t*16+l15]
            // Q pre-scaled by log2e -> bare v_exp_f32 (builtin). no-max softmax: |score| small.
            float p0[4], p1[4];
            p0[0] = exp2_native(c0[0]) * m0v.x;  p0[1] = exp2_native(c0[1]) * m0v.y;
            p0[2] = exp2_native(c0[2]) * m0v.z;  p0[3] = exp2_native(c0[3]) * m0v.w;
            p1[0] = exp2_native(c1[0]) * m1v.x;  p1[1] = exp2_native(c1[1]) * m1v.y;
            p1[2] = exp2_native(c1[2]) * m1v.z;  p1[3] = exp2_native(c1[3]) * m1v.w;
            lsum[t] += ((p0[0] + p0[1]) + (p0[2] + p0[3]))
                     + ((p1[0] + p1[1]) + (p1[2] + p1[3]));
            // pack P via constant-index vector inserts (SSA; compiler emits cvt_pk pairs)
            bf16x8 pv;
            pv[0] = (__bf16)p0[0]; pv[1] = (__bf16)p0[1];
            pv[2] = (__bf16)p0[2]; pv[3] = (__bf16)p0[3];
            pv[4] = (__bf16)p1[0]; pv[5] = (__bf16)p1[1];
            pv[6] = (__bf16)p1[2]; pv[7] = (__bf16)p1[3];
            o[t][0] = __builtin_amdgcn_mfma_f32_16x16x32_bf16(pv, vf0, o[t][0], 0, 0, 0);
            o[t][1] = __builtin_amdgcn_mfma_f32_16x16x32_bf16(pv, vf1, o[t][1], 0, 0, 0);
            o[t][2] = __builtin_amdgcn_mfma_f32_16x16x32_bf16(pv, vf2, o[t][2], 0, 0, 0);
            o[t][3] = __builtin_amdgcn_mfma_f32_16x16x32_bf16(pv, vf3, o[t][3], 0, 0, 0);
        }
    }

    // epilogue: lsum[t] is per-lane partial (this lane's keys) for q = t*16+l15.
    // Reduce across quads, then redistribute to the output layout (q = quad*4+r).
    #pragma unroll
    for (int t = 0; t < 4; ++t) {
        float l = lsum[t];
        l += __shfl_xor(l, 16);
        l += __shfl_xor(l, 32);          // all lanes: full sum for q = t*16 + l15
        #pragma unroll
        for (int r = 0; r < 4; ++r) {
            float lv = __shfl(l, quad * 4 + r);   // sum for q = t*16 + quad*4 + r
            float inv = (lv > 0.f) ? 1.f / lv : 0.f;   // all-masked row -> 0 (matches NaN->0)
            int row = s0 + t * 16 + quad * 4 + r;
            u16* xb = xobf + (size_t)e * EMAT + (size_t)(b * 512 + row) * CC + h * 64;
            #pragma unroll
            for (int j = 0; j < 4; ++j)
                xb[j * 16 + l15] = f2bf_hw(o[t][j][r] * inv);
        }
    }
}

// ---------- aggregated = sum_e sparse[b,s,e] * stacked[b,s,e,c] ----------
__global__ __launch_bounds__(256) void aggregate_k(
    const float* __restrict__ stacked, const float* __restrict__ sparse, float* __restrict__ agg) {
    int idx = blockIdx.x * 256 + threadIdx.x;
    int m = idx >> 7;
    int c4 = (idx & 127) << 2;
    const float* sp = sparse + (size_t)m * NE;
    float4 a = {0.f, 0.f, 0.f, 0.f};
    #pragma unroll
    for (int e = 0; e < NE; ++e) {
        float s = sp[e];
        float4 v = *(const float4*)(stacked + ((size_t)m * NE + e) * CC + c4);
        a.x = fmaf(s, v.x, a.x); a.y = fmaf(s, v.y, a.y);
        a.z = fmaf(s, v.z, a.z); a.w = fmaf(s, v.w, a.w);
    }
    ((float4*)agg)[idx] = a;
}

extern "C" void kernel_launch(void* const* d_in, const int* in_sizes, int n_in,
                              void* d_out, int out_size, void* d_ws, size_t ws_size,
                              hipStream_t stream) {
    const float* x   = (const float*)d_in[0];
    const void*  mask = d_in[1];
    const float* qw = (const float*)d_in[2];   const float* qb = (const float*)d_in[3];
    const float* kw = (const float*)d_in[4];   const float* kb = (const float*)d_in[5];
    const float* vw = (const float*)d_in[6];   const float* vb = (const float*)d_in[7];
    const float* f1w = (const float*)d_in[8];  const float* f1b = (const float*)d_in[9];
    const float* f2w = (const float*)d_in[10]; const float* f2b = (const float*)d_in[11];
    const float* rw1 = (const float*)d_in[12]; const float* rb1 = (const float*)d_in[13];
    const float* rw2 = (const float*)d_in[14]; const float* rb2 = (const float*)d_in[15];

    float* out = (float*)d_out;
    float* agg     = out;                 // (B,S,C)      2,097,152
    float* stacked = out + 2097152;       // (B,S,E,C)   12,582,912
    float* sparse  = out + 14680064;      // (B,S,E)         24,576

    char* ws = (char*)d_ws;
    int* flag = (int*)(ws + FLAG_OFF);
    u16* xbf = (u16*)(ws + XBF_OFF);
    u16* wt  = (u16*)(ws + WT_OFF);
    u16* qbf = (u16*)(ws + QBF_OFF);
    u16* kbf = (u16*)(ws + KBF_OFF);
    u16* vt  = (u16*)(ws + VT_OFF);
    u16* xob = (u16*)(ws + XO_OFF);
    u16* hbf = (u16*)(ws + HBF_OFF);
    float* rh = (float*)(ws + RH_OFF);

    detect_mask_k<<<1, 256, 0, stream>>>((const u32*)mask, flag);
    cast_x_k<<<2048, 256, 0, stream>>>(x, xbf);
    transpose_w_k<<<dim3(256, 30), 256, 0, stream>>>(qw, kw, vw, f1w, f2w, wt);
    router_rh_k<<<dim3(8, 64), 256, 0, stream>>>(x, rw1, rb1, rh);
    router_topk_k<<<1024, 256, 0, stream>>>(rh, rw2, rb2, sparse);

    dim3 gg(4, 32, 6);
    gemm_k<0><<<gg, 256, 0, stream>>>(xbf, wt, qbf, nullptr, nullptr, qb);
    gemm_k<1><<<gg, 256, 0, stream>>>(xbf, wt, kbf, nullptr, nullptr, kb);
    gemm_k<2><<<gg, 256, 0, stream>>>(xbf, wt, vt,  nullptr, nullptr, vb);
    attn_flash_k<<<dim3(2, 64, 6), 256, 0, stream>>>(qbf, kbf, vt, xob, mask, flag);
    gemm_k<3><<<gg, 256, 0, stream>>>(xob, wt, hbf, nullptr, nullptr, f1b);
    gemm_k<4><<<gg, 256, 0, stream>>>(hbf, wt, nullptr, stacked, xob, f2b);
    aggregate_k<<<2048, 256, 0, stream>>>(stacked, sparse, agg);
}

// Round 11
// 370.651 us; speedup vs baseline: 1.0118x; 1.0118x over previous
//
#include <hip/hip_runtime.h>

typedef unsigned short u16;
typedef unsigned int   u32;
typedef unsigned long long u64;
typedef __bf16 bf16x8 __attribute__((ext_vector_type(8)));
typedef float  f32x4  __attribute__((ext_vector_type(4)));

// Problem constants
#define NE    6          // experts
#define MTOT  4096       // B*S
#define CC    512        // C
#define BMAT  262144     // 512*512
#define EMAT  2097152    // 4096*512

// ws layout (bytes). Total need ~154.2 MB.
#define FLAG_OFF 0
#define XBF_OFF  256
#define WT_OFF   (XBF_OFF + MTOT*CC*2)          // x bf16: 4 MB
#define QBF_OFF  (WT_OFF  + 30*BMAT*2)          // 30 transposed bf16 weights: 15.7 MB
#define KBF_OFF  (QBF_OFF + NE*EMAT*2)
#define VT_OFF   (KBF_OFF + NE*EMAT*2)
#define XO_OFF   (VT_OFF  + NE*EMAT*2)
#define HBF_OFF  (XO_OFF  + NE*EMAT*2)
#define RH_OFF   (HBF_OFF + NE*EMAT*2)          // rh fp32: 8 MB

__device__ __forceinline__ u16 f2bf(float f) {
    u32 u = __float_as_uint(f);
    u32 r = (u + 0x7FFFu + ((u >> 16) & 1u)) >> 16;
    return (u16)r;
}
__device__ __forceinline__ u16 f2bf_hw(float f) {   // native RNE cvt (1 VALU op)
    __bf16 h = (__bf16)f;
    return *(u16*)&h;
}
__device__ __forceinline__ float bf2f(u16 h) {
    return __uint_as_float(((u32)h) << 16);
}
// native 2^x as a COMPILER-KNOWN instruction: MFMA->VALU and TRANS-latency
// hazards are software-managed; the hazard recognizer only protects known
// instructions. NO INLINE ASM may touch the MFMA/TRANS dataflow (R2: asm exp
// read the MFMA accumulator early -> NaN; R3: asm cvt_pk read the TRANS exp
// result early -> sporadic garbage P).
__device__ __forceinline__ float exp2_native(float x) {
#if __has_builtin(__builtin_amdgcn_exp2f)
    return __builtin_amdgcn_exp2f(x);
#else
    return exp2f(x);
#endif
}
__device__ __forceinline__ float gelu_exact(float x) {
    return 0.5f * x * (1.0f + erff(x * 0.70710678118654752f));
}
__device__ __forceinline__ bool mask_valid(const void* mask, int flag, int b, int t) {
    int idx = b * 1536 + t;   // mask is (B, 3S), use first S cols
    if (flag == 1) return ((const int*)mask)[idx] != 0;
    if (flag == 2) return ((const float*)mask)[idx] != 0.0f;
    return ((const unsigned char*)mask)[idx] != 0;
}

// ---------- mask dtype detection (bool may arrive as u8 / i32 / f32) ----------
__global__ void detect_mask_k(const u32* __restrict__ m, int* __restrict__ flag) {
    __shared__ int notint, notfloat;
    if (threadIdx.x == 0) { notint = 0; notfloat = 0; }
    __syncthreads();
    int ni = 0, nf = 0;
    for (int i = threadIdx.x; i < 3072; i += 256) {
        u32 v = m[i];
        if (v > 1u) ni = 1;
        if (v != 0u && v != 0x3F800000u) nf = 1;
    }
    if (ni) notint = 1;
    if (nf) notfloat = 1;
    __syncthreads();
    if (threadIdx.x == 0) *flag = (notint == 0) ? 1 : ((notfloat == 0) ? 2 : 0);
}

// ---------- x fp32 -> bf16 ----------
__global__ __launch_bounds__(256) void cast_x_k(const float* __restrict__ x, u16* __restrict__ xbf) {
    int i = blockIdx.x * 256 + threadIdx.x;
    float4 v = ((const float4*)x)[i];
    u64 pk = (u64)f2bf(v.x) | ((u64)f2bf(v.y) << 16) | ((u64)f2bf(v.z) << 32) | ((u64)f2bf(v.w) << 48);
    *(u64*)(xbf + (size_t)i * 4) = pk;
}

// ---------- weights fp32 [k][n] -> bf16 transposed [n][k] ----------
__global__ __launch_bounds__(256) void transpose_w_k(
    const float* __restrict__ qw, const float* __restrict__ kw, const float* __restrict__ vw,
    const float* __restrict__ f1w, const float* __restrict__ f2w, u16* __restrict__ wt) {
    int mat = blockIdx.y;
    int tile = blockIdx.x;
    int tr = tile >> 4, tc = tile & 15;
    const float* srcs[5] = {qw, kw, vw, f1w, f2w};
    const float* src = srcs[mat / 6] + (size_t)(mat % 6) * BMAT;
    u16* dst = wt + (size_t)mat * BMAT;
    __shared__ float tb[32][33];
    int r = threadIdx.x >> 5, c = threadIdx.x & 31;
    #pragma unroll
    for (int i = 0; i < 4; ++i)
        tb[r + i * 8][c] = src[(size_t)(tr * 32 + r + i * 8) * CC + tc * 32 + c];
    __syncthreads();
    #pragma unroll
    for (int i = 0; i < 4; ++i)
        dst[(size_t)(tc * 32 + r + i * 8) * CC + tr * 32 + c] = f2bf(tb[c][r + i * 8]);
}

// ---------- fp32 tiled GEMM for router rh = gelu(X @ rw1 + rb1) ----------
// R9: A-tile stored TRANSPOSED At[k][m]: inner loop reads a[0..3] as one broadcast
// ds_read_b128 and b[0..3] as one 2-way b128 (vs 8 scalar b32). Accumulation order
// unchanged -> bit-identical rh; router stays fp32-exact (top-2 must not flip).
__global__ __launch_bounds__(256) void router_rh_k(
    const float* __restrict__ x, const float* __restrict__ rw1, const float* __restrict__ rb1,
    float* __restrict__ rh) {
    const int n0 = blockIdx.x * 64, m0 = blockIdx.y * 64;
    const int tid = threadIdx.x, tx = tid & 15, ty = tid >> 4;
    __shared__ float At[16][68];
    __shared__ float Bs[16][68];
    float acc[4][4] = {};
    for (int kt = 0; kt < 32; ++kt) {
        int ar = tid >> 2, ak = (tid & 3) * 4;
        float4 av = *(const float4*)(x + (size_t)(m0 + ar) * CC + kt * 16 + ak);
        int br = tid >> 4, bn = (tid & 15) * 4;
        float4 bv = *(const float4*)(rw1 + (size_t)(kt * 16 + br) * CC + n0 + bn);
        __syncthreads();
        At[ak + 0][ar] = av.x; At[ak + 1][ar] = av.y;
        At[ak + 2][ar] = av.z; At[ak + 3][ar] = av.w;
        *(float4*)&Bs[br][bn] = bv;
        __syncthreads();
        #pragma unroll
        for (int k = 0; k < 16; ++k) {
            float4 a4 = *(const float4*)&At[k][ty * 4];
            float4 b4 = *(const float4*)&Bs[k][tx * 4];
            acc[0][0] = fmaf(a4.x, b4.x, acc[0][0]); acc[0][1] = fmaf(a4.x, b4.y, acc[0][1]);
            acc[0][2] = fmaf(a4.x, b4.z, acc[0][2]); acc[0][3] = fmaf(a4.x, b4.w, acc[0][3]);
            acc[1][0] = fmaf(a4.y, b4.x, acc[1][0]); acc[1][1] = fmaf(a4.y, b4.y, acc[1][1]);
            acc[1][2] = fmaf(a4.y, b4.z, acc[1][2]); acc[1][3] = fmaf(a4.y, b4.w, acc[1][3]);
            acc[2][0] = fmaf(a4.z, b4.x, acc[2][0]); acc[2][1] = fmaf(a4.z, b4.y, acc[2][1]);
            acc[2][2] = fmaf(a4.z, b4.z, acc[2][2]); acc[2][3] = fmaf(a4.z, b4.w, acc[2][3]);
            acc[3][0] = fmaf(a4.w, b4.x, acc[3][0]); acc[3][1] = fmaf(a4.w, b4.y, acc[3][1]);
            acc[3][2] = fmaf(a4.w, b4.z, acc[3][2]); acc[3][3] = fmaf(a4.w, b4.w, acc[3][3]);
        }
    }
    #pragma unroll
    for (int i = 0; i < 4; ++i) {
        int m = m0 + ty * 4 + i;
        #pragma unroll
        for (int j = 0; j < 4; ++j) {
            int n = n0 + tx * 4 + j;
            rh[(size_t)m * CC + n] = gelu_exact(acc[i][j] + rb1[n]);
        }
    }
}

// ---------- router: logits, softmax, top-2, normalized sparse weights ----------
__global__ __launch_bounds__(256) void router_topk_k(
    const float* __restrict__ rh, const float* __restrict__ rw2, const float* __restrict__ rb2,
    float* __restrict__ sparse) {
    int row = blockIdx.x * 4 + (threadIdx.x >> 6);
    int lane = threadIdx.x & 63;
    float acc[NE] = {};
    const float* rr = rh + (size_t)row * CC;
    for (int c = 0; c < 8; ++c) {
        int k = c * 64 + lane;
        float v = rr[k];
        const float* w = rw2 + (size_t)k * NE;
        #pragma unroll
        for (int e = 0; e < NE; ++e) acc[e] = fmaf(v, w[e], acc[e]);
    }
    #pragma unroll
    for (int off = 32; off; off >>= 1)
        #pragma unroll
        for (int e = 0; e < NE; ++e) acc[e] += __shfl_down(acc[e], off);
    if (lane == 0) {
        float lg[NE], m = -1e30f;
        #pragma unroll
        for (int e = 0; e < NE; ++e) { lg[e] = acc[e] + rb2[e]; m = fmaxf(m, lg[e]); }
        float s = 0.f, wv[NE];
        #pragma unroll
        for (int e = 0; e < NE; ++e) { wv[e] = expf(lg[e] - m); s += wv[e]; }
        #pragma unroll
        for (int e = 0; e < NE; ++e) wv[e] /= s;
        int i1 = 0; float v1 = wv[0];
        #pragma unroll
        for (int e = 1; e < NE; ++e) if (wv[e] > v1) { v1 = wv[e]; i1 = e; }
        int i2 = -1; float v2 = -1.f;
        #pragma unroll
        for (int e = 0; e < NE; ++e) if (e != i1 && wv[e] > v2) { v2 = wv[e]; i2 = e; }
        float denom = fmaxf(v1 + v2, 1e-8f);
        #pragma unroll
        for (int e = 0; e < NE; ++e)
            sparse[(size_t)row * NE + e] = ((e == i1) ? v1 : (e == i2) ? v2 : 0.f) / denom;
    }
}

// ---------- bf16 MFMA GEMM, compile-time MODE epilogue ----------
// MODE 0: Q = (x@qwT + qb)*scale*log2e -> bf16  (A=xbf shared across e; log2e folded so attn uses exp2)
// MODE 1: K =  x@kwT + kb        -> bf16
// MODE 2: V =  x@vwT + vb        -> bf16 TRANSPOSED [e][n][m_perm]  (m permuted per 32-block, see attn)
// MODE 3: H = gelu(xo@fc1T + b)  -> bf16      (A=xobf per e)
// MODE 4: stacked = xo + H@fc2T + b -> fp32   (A=hbf per e, resid=xobf)
// R11: XCD-aware tile assignment (T1). Grid flattened to 1D (768 = 8 XCDs x 96,
// nwg%8==0 -> bijective). Default 3D order put ONE bx, HALF the by's, ALL experts on
// each XCD = 96 distinct A-panels (12 MB) thrashing a 4 MB XCD-L2 (R8 gemm counters:
// FETCH 52 MB vs ~7 ideal, 1.1 TB/s effective -> L2-miss-latency-bound). New map: XCD
// x hosts 24 (by,e) A-panels with all 4 bx-sharers at CONSECUTIVE slots (A fetched once
// per XCD, tight reuse) + 24 B-panels = 6 MB/XCD. Same tiles, same per-tile arithmetic
// -> bit-identical output.
// R8 lesson kept: reg-staged (loads issue BEFORE the barrier = free prefetch);
// single-buffered gload_lds phase-locks at short K. R10: BK=64 neutral -> BK=32.
template<int MODE>
__global__ __launch_bounds__(256, 3) void gemm_k(
    const u16* __restrict__ A0, const u16* __restrict__ wt,
    u16* __restrict__ out_bf, float* __restrict__ out_f32,
    const u16* __restrict__ resid, const float* __restrict__ bias0) {
    // XCD-aware decode: xcd = bid&7 (HW round-robin), slot = bid>>3.
    const int bid = blockIdx.x;
    const int xcd = bid & 7, slot = bid >> 3;
    const int bx = slot & 3, pair = slot >> 2;
    const int eby = xcd + pair * 8;          // 0..191, bijective
    const int e = eby >> 5, by = eby & 31;

    const u16* A  = (MODE <= 2) ? A0 : (A0 + (size_t)e * EMAT);
    const int wmat = (MODE == 0 ? 0 : MODE == 1 ? 6 : MODE == 2 ? 12 : MODE == 3 ? 18 : 24) + e;
    const u16* BT = wt + (size_t)wmat * BMAT;
    const float* bias = bias0 + e * CC;

    const int m0 = by * 128, n0 = bx * 128;
    const int tid = threadIdx.x, lane = tid & 63, wv = tid >> 6;
    const int l15 = lane & 15, quad = lane >> 4;
    const int wr = (wv >> 1) * 64, wc = (wv & 1) * 64;

    __shared__ u16 As[128 * 40];
    __shared__ u16 Bs[128 * 40];

    f32x4 acc[4][4];
    f32x4 z4 = {0.f, 0.f, 0.f, 0.f};
    #pragma unroll
    for (int i = 0; i < 4; ++i)
        #pragma unroll
        for (int j = 0; j < 4; ++j) acc[i][j] = z4;

    const int row2 = tid >> 1, half = tid & 1;
    const u16* agp = A  + (size_t)(m0 + row2) * CC + half * 16;
    const u16* bgp = BT + (size_t)(n0 + row2) * CC + half * 16;
    u16* asp = As + row2 * 40 + half * 16;
    u16* bsp = Bs + row2 * 40 + half * 16;

    for (int kt = 0; kt < 16; ++kt) {
        uint4 a0 = *(const uint4*)(agp + kt * 32);
        uint4 a1 = *(const uint4*)(agp + kt * 32 + 8);
        uint4 b0 = *(const uint4*)(bgp + kt * 32);
        uint4 b1 = *(const uint4*)(bgp + kt * 32 + 8);
        __syncthreads();
        *(uint4*)asp = a0; *(uint4*)(asp + 8) = a1;
        *(uint4*)bsp = b0; *(uint4*)(bsp + 8) = b1;
        __syncthreads();
        bf16x8 af[4], bf[4];
        #pragma unroll
        for (int i = 0; i < 4; ++i) af[i] = *(const bf16x8*)(As + (wr + i * 16 + l15) * 40 + quad * 8);
        #pragma unroll
        for (int j = 0; j < 4; ++j) bf[j] = *(const bf16x8*)(Bs + (wc + j * 16 + l15) * 40 + quad * 8);
        #pragma unroll
        for (int i = 0; i < 4; ++i)
            #pragma unroll
            for (int j = 0; j < 4; ++j)
                acc[i][j] = __builtin_amdgcn_mfma_f32_16x16x32_bf16(af[i], bf[j], acc[i][j], 0, 0, 0);
    }

    #pragma unroll
    for (int i = 0; i < 4; ++i) {
        int mb = m0 + wr + i * 16 + quad * 4;
        #pragma unroll
        for (int j = 0; j < 4; ++j) {
            int n = n0 + wc + j * 16 + l15;
            float bvs = bias[n];
            if (MODE == 2) {
                // V: transposed store [e][n][m_perm]. Within each 32-key block of m,
                // key km = hi*16 + q*4 + r is stored at position q*8 + hi*4 + r, so the
                // attn PV B-fragment (lane quad reads 8 keys {q*4+0..3, 16+q*4+0..3})
                // is one contiguous 16B load at offset quad*8.
                u16 pk[4];
                #pragma unroll
                for (int r = 0; r < 4; ++r) pk[r] = f2bf(acc[i][j][r] + bvs);
                u64 w8 = (u64)pk[0] | ((u64)pk[1] << 16) | ((u64)pk[2] << 32) | ((u64)pk[3] << 48);
                int mp = (mb & ~31) | (((mb >> 2) & 3) << 3) | (((mb >> 4) & 1) << 2);
                *(u64*)(out_bf + (size_t)e * EMAT + (size_t)n * MTOT + mp) = w8;
            } else if (MODE == 0 || MODE == 1) {
                #pragma unroll
                for (int r = 0; r < 4; ++r) {
                    float v = acc[i][j][r] + bvs;
                    // 0.125 * log2(e): attn computes exp2 directly (1 VTRANS, no pre-mul)
                    out_bf[(size_t)e * EMAT + (size_t)(mb + r) * CC + n] =
                        f2bf(MODE == 0 ? v * 0.18033688011112042f : v);
                }
            } else if (MODE == 3) {
                #pragma unroll
                for (int r = 0; r < 4; ++r)
                    out_bf[(size_t)e * EMAT + (size_t)(mb + r) * CC + n] = f2bf(gelu_exact(acc[i][j][r] + bvs));
            } else {
                #pragma unroll
                for (int r = 0; r < 4; ++r) {
                    int m = mb + r;
                    float v = acc[i][j][r] + bvs + bf2f(resid[(size_t)e * EMAT + (size_t)m * CC + n]);
                    out_f32[((size_t)m * NE + e) * CC + n] = v;
                }
            }
        }
    }
}

// ---------- flash attention v6: swapped QK^T, in-register P, permuted V, loads-at-use ----------
// S^T = mfma(K, Q): lane holds P for one q-row (q = lane&15) at keys {quad*4+r, 16+quad*4+r}.
// P packed to a bf16x8 PV A-fragment via constant-index vector inserts (SSA; compiler emits
// v_cvt_pk_bf16_f32 pairs). V STORED permuted (gemm_k<2>) so its B-fragment is one 16B load.
// No LDS P round-trip, no bank conflicts, no cross-lane ops.
// REGISTER BUDGET (R4/R5 lesson): __launch_bounds__(256,3) caps unified VGPR+AGPR at ~168.
// Deep register pipelines spill (WRITE_SIZE 950 MB signature). Per-chunk NAMED K/V
// temporaries, loads-at-use, ~150 regs, no spill. Known limit (R6/R9 counters):
// memory-latency-bound at 18% HBM.
// Correctness invariant (R2/R3): ZERO inline asm in the MFMA/TRANS dataflow.
// grid (2, b*8+h, e); block 256 (4 independent waves).
__global__ __launch_bounds__(256, 3) void attn_flash_k(
    const u16* __restrict__ qbf, const u16* __restrict__ kbf, const u16* __restrict__ vt,
    u16* __restrict__ xobf, const void* __restrict__ mask, const int* __restrict__ flagp) {
    const int b = blockIdx.y >> 3, h = blockIdx.y & 7;
    const int e = blockIdx.z;
    const int tid = threadIdx.x, lane = tid & 63, w = tid >> 6;
    const int l15 = lane & 15, quad = lane >> 4;
    const int s0 = blockIdx.x * 256 + w * 64;     // this wave's 64 q-rows (local s)
    const int flag = *flagp;

    // mask as float, staged once (2 KB LDS). Read per chunk as two float4.
    __shared__ float mlds[512];
    mlds[tid]       = mask_valid(mask, flag, b, tid)       ? 1.f : 0.f;
    mlds[tid + 256] = mask_valid(mask, flag, b, tid + 256) ? 1.f : 0.f;
    __syncthreads();

    const u16* qbase = qbf + (size_t)e * EMAT + (size_t)(b * 512) * CC + h * 64;
    const u16* kbase = kbf + (size_t)e * EMAT + (size_t)(b * 512) * CC + h * 64;
    const u16* vbase = vt  + (size_t)e * EMAT + (size_t)(h * 64) * MTOT + b * 512;

    bf16x8 qa[4][2];
    #pragma unroll
    for (int t = 0; t < 4; ++t) {
        qa[t][0] = *(const bf16x8*)(qbase + (size_t)(s0 + t * 16 + l15) * CC + quad * 8);
        qa[t][1] = *(const bf16x8*)(qbase + (size_t)(s0 + t * 16 + l15) * CC + 32 + quad * 8);
    }

    float lsum[4] = {0.f, 0.f, 0.f, 0.f};
    f32x4 o[4][4];
    f32x4 z4 = {0.f, 0.f, 0.f, 0.f};
    #pragma unroll
    for (int t = 0; t < 4; ++t)
        #pragma unroll
        for (int j = 0; j < 4; ++j) o[t][j] = z4;

    for (int ch = 0; ch < 16; ++ch) {
        const int k0 = ch * 32;
        // K fragments, loaded at use (named temporaries -- per-chunk lifetime only)
        bf16x8 kb00 = *(const bf16x8*)(kbase + (size_t)(k0 + l15) * CC + quad * 8);
        bf16x8 kb01 = *(const bf16x8*)(kbase + (size_t)(k0 + l15) * CC + 32 + quad * 8);
        bf16x8 kb10 = *(const bf16x8*)(kbase + (size_t)(k0 + 16 + l15) * CC + quad * 8);
        bf16x8 kb11 = *(const bf16x8*)(kbase + (size_t)(k0 + 16 + l15) * CC + 32 + quad * 8);
        // V fragments: single 16B load each thanks to the permuted store
        bf16x8 vf0 = *(const bf16x8*)(vbase + (size_t)(0 * 16 + l15) * MTOT + k0 + quad * 8);
        bf16x8 vf1 = *(const bf16x8*)(vbase + (size_t)(1 * 16 + l15) * MTOT + k0 + quad * 8);
        bf16x8 vf2 = *(const bf16x8*)(vbase + (size_t)(2 * 16 + l15) * MTOT + k0 + quad * 8);
        bf16x8 vf3 = *(const bf16x8*)(vbase + (size_t)(3 * 16 + l15) * MTOT + k0 + quad * 8);
        float4 m0v = *(const float4*)(mlds + k0 + quad * 4);
        float4 m1v = *(const float4*)(mlds + k0 + 16 + quad * 4);

        #pragma unroll
        for (int t = 0; t < 4; ++t) {
            f32x4 c0 = z4, c1 = z4;
            c0 = __builtin_amdgcn_mfma_f32_16x16x32_bf16(kb00, qa[t][0], c0, 0, 0, 0);
            c0 = __builtin_amdgcn_mfma_f32_16x16x32_bf16(kb01, qa[t][1], c0, 0, 0, 0);
            c1 = __builtin_amdgcn_mfma_f32_16x16x32_bf16(kb10, qa[t][0], c1, 0, 0, 0);
            c1 = __builtin_amdgcn_mfma_f32_16x16x32_bf16(kb11, qa[t][1], c1, 0, 0, 0);
            // lane: S^T[key = quad*4+r (c0) / 16+quad*4+r (c1)][q = t*16+l15]
            // Q pre-scaled by log2e -> bare v_exp_f32 (builtin). no-max softmax: |score| small.
            float p0[4], p1[4];
            p0[0] = exp2_native(c0[0]) * m0v.x;  p0[1] = exp2_native(c0[1]) * m0v.y;
            p0[2] = exp2_native(c0[2]) * m0v.z;  p0[3] = exp2_native(c0[3]) * m0v.w;
            p1[0] = exp2_native(c1[0]) * m1v.x;  p1[1] = exp2_native(c1[1]) * m1v.y;
            p1[2] = exp2_native(c1[2]) * m1v.z;  p1[3] = exp2_native(c1[3]) * m1v.w;
            lsum[t] += ((p0[0] + p0[1]) + (p0[2] + p0[3]))
                     + ((p1[0] + p1[1]) + (p1[2] + p1[3]));
            // pack P via constant-index vector inserts (SSA; compiler emits cvt_pk pairs)
            bf16x8 pv;
            pv[0] = (__bf16)p0[0]; pv[1] = (__bf16)p0[1];
            pv[2] = (__bf16)p0[2]; pv[3] = (__bf16)p0[3];
            pv[4] = (__bf16)p1[0]; pv[5] = (__bf16)p1[1];
            pv[6] = (__bf16)p1[2]; pv[7] = (__bf16)p1[3];
            o[t][0] = __builtin_amdgcn_mfma_f32_16x16x32_bf16(pv, vf0, o[t][0], 0, 0, 0);
            o[t][1] = __builtin_amdgcn_mfma_f32_16x16x32_bf16(pv, vf1, o[t][1], 0, 0, 0);
            o[t][2] = __builtin_amdgcn_mfma_f32_16x16x32_bf16(pv, vf2, o[t][2], 0, 0, 0);
            o[t][3] = __builtin_amdgcn_mfma_f32_16x16x32_bf16(pv, vf3, o[t][3], 0, 0, 0);
        }
    }

    // epilogue: lsum[t] is per-lane partial (this lane's keys) for q = t*16+l15.
    // Reduce across quads, then redistribute to the output layout (q = quad*4+r).
    #pragma unroll
    for (int t = 0; t < 4; ++t) {
        float l = lsum[t];
        l += __shfl_xor(l, 16);
        l += __shfl_xor(l, 32);          // all lanes: full sum for q = t*16 + l15
        #pragma unroll
        for (int r = 0; r < 4; ++r) {
            float lv = __shfl(l, quad * 4 + r);   // sum for q = t*16 + quad*4 + r
            float inv = (lv > 0.f) ? 1.f / lv : 0.f;   // all-masked row -> 0 (matches NaN->0)
            int row = s0 + t * 16 + quad * 4 + r;
            u16* xb = xobf + (size_t)e * EMAT + (size_t)(b * 512 + row) * CC + h * 64;
            #pragma unroll
            for (int j = 0; j < 4; ++j)
                xb[j * 16 + l15] = f2bf_hw(o[t][j][r] * inv);
        }
    }
}

// ---------- aggregated = sum_e sparse[b,s,e] * stacked[b,s,e,c] ----------
__global__ __launch_bounds__(256) void aggregate_k(
    const float* __restrict__ stacked, const float* __restrict__ sparse, float* __restrict__ agg) {
    int idx = blockIdx.x * 256 + threadIdx.x;
    int m = idx >> 7;
    int c4 = (idx & 127) << 2;
    const float* sp = sparse + (size_t)m * NE;
    float4 a = {0.f, 0.f, 0.f, 0.f};
    #pragma unroll
    for (int e = 0; e < NE; ++e) {
        float s = sp[e];
        float4 v = *(const float4*)(stacked + ((size_t)m * NE + e) * CC + c4);
        a.x = fmaf(s, v.x, a.x); a.y = fmaf(s, v.y, a.y);
        a.z = fmaf(s, v.z, a.z); a.w = fmaf(s, v.w, a.w);
    }
    ((float4*)agg)[idx] = a;
}

extern "C" void kernel_launch(void* const* d_in, const int* in_sizes, int n_in,
                              void* d_out, int out_size, void* d_ws, size_t ws_size,
                              hipStream_t stream) {
    const float* x   = (const float*)d_in[0];
    const void*  mask = d_in[1];
    const float* qw = (const float*)d_in[2];   const float* qb = (const float*)d_in[3];
    const float* kw = (const float*)d_in[4];   const float* kb = (const float*)d_in[5];
    const float* vw = (const float*)d_in[6];   const float* vb = (const float*)d_in[7];
    const float* f1w = (const float*)d_in[8];  const float* f1b = (const float*)d_in[9];
    const float* f2w = (const float*)d_in[10]; const float* f2b = (const float*)d_in[11];
    const float* rw1 = (const float*)d_in[12]; const float* rb1 = (const float*)d_in[13];
    const float* rw2 = (const float*)d_in[14]; const float* rb2 = (const float*)d_in[15];

    float* out = (float*)d_out;
    float* agg     = out;                 // (B,S,C)      2,097,152
    float* stacked = out + 2097152;       // (B,S,E,C)   12,582,912
    float* sparse  = out + 14680064;      // (B,S,E)         24,576

    char* ws = (char*)d_ws;
    int* flag = (int*)(ws + FLAG_OFF);
    u16* xbf = (u16*)(ws + XBF_OFF);
    u16* wt  = (u16*)(ws + WT_OFF);
    u16* qbf = (u16*)(ws + QBF_OFF);
    u16* kbf = (u16*)(ws + KBF_OFF);
    u16* vt  = (u16*)(ws + VT_OFF);
    u16* xob = (u16*)(ws + XO_OFF);
    u16* hbf = (u16*)(ws + HBF_OFF);
    float* rh = (float*)(ws + RH_OFF);

    detect_mask_k<<<1, 256, 0, stream>>>((const u32*)mask, flag);
    cast_x_k<<<2048, 256, 0, stream>>>(x, xbf);
    transpose_w_k<<<dim3(256, 30), 256, 0, stream>>>(qw, kw, vw, f1w, f2w, wt);
    router_rh_k<<<dim3(8, 64), 256, 0, stream>>>(x, rw1, rb1, rh);
    router_topk_k<<<1024, 256, 0, stream>>>(rh, rw2, rb2, sparse);

    gemm_k<0><<<768, 256, 0, stream>>>(xbf, wt, qbf, nullptr, nullptr, qb);
    gemm_k<1><<<768, 256, 0, stream>>>(xbf, wt, kbf, nullptr, nullptr, kb);
    gemm_k<2><<<768, 256, 0, stream>>>(xbf, wt, vt,  nullptr, nullptr, vb);
    attn_flash_k<<<dim3(2, 64, 6), 256, 0, stream>>>(qbf, kbf, vt, xob, mask, flag);
    gemm_k<3><<<768, 256, 0, stream>>>(xob, wt, hbf, nullptr, nullptr, f1b);
    gemm_k<4><<<768, 256, 0, stream>>>(hbf, wt, nullptr, stacked, xob, f2b);
    aggregate_k<<<2048, 256, 0, stream>>>(stacked, sparse, agg);
}